// Round 7
// baseline (139.545 us; speedup 1.0000x reference)
//
#include <hip/hip_runtime.h>
#include <hip/hip_bf16.h>

#define NPTS 8192
#define NB 4
#define NC 13
#define KTOP 16
#define RPB 16        // rows (sorted queries) per block: 4 waves x 4 rows
#define CAP 150       // per-row candidate capacity
#define CAPP 151      // padded stride
#define NTILES 128    // tiles per batch (64 sorted pts each)
#define WIN 7         // init-window tiles (448 pts)

typedef unsigned long long ull;

__device__ __forceinline__ float rfl(float x) {
    return __uint_as_float(__builtin_amdgcn_readfirstlane(__float_as_uint(x)));
}
__device__ __forceinline__ unsigned sortable(float s) {
    unsigned u = __float_as_uint(s);
    return u ^ ((u & 0x80000000u) ? 0xFFFFFFFFu : 0x80000000u);
}
__device__ __forceinline__ unsigned spread3(unsigned v) {   // bits -> 0,3,6
    return (v & 1u) | ((v & 2u) << 2) | ((v & 4u) << 4);
}
__device__ __forceinline__ unsigned cellcode(float x, float y, float z) {
    unsigned cx = (unsigned)min(max((int)floorf(x) + 4, 0), 7);
    unsigned cy = (unsigned)min(max((int)floorf(y) + 4, 0), 7);
    unsigned cz = (unsigned)min(max((int)floorf(z) + 4, 0), 7);
    return spread3(cx) | (spread3(cy) << 1) | (spread3(cz) << 2);   // 9-bit Morton
}

// ---------------- prep 0: zero histograms ----------------
__global__ __launch_bounds__(256) void zero_kernel(unsigned* __restrict__ hist) {
    hist[blockIdx.x * 256 + threadIdx.x] = 0u;    // grid 8 -> 2048 counters
}

// ---------------- prep 1: cell histogram + softmax transpose ----------------
__global__ __launch_bounds__(256) void hist_kernel(
    const float* __restrict__ logits, const float* __restrict__ xyz,
    unsigned* __restrict__ hist, float4* __restrict__ probst)
{
    int gid = blockIdx.x * 256 + threadIdx.x;     // 0 .. B*N-1
    int b = gid >> 13, n = gid & (NPTS - 1);

    const float* xb = xyz + b * 3 * NPTS;
    float x = xb[n], y = xb[NPTS + n], z = xb[2 * NPTS + n];
    atomicAdd(&hist[b * 512 + cellcode(x, y, z)], 1u);

    const float* lb = logits + b * NC * NPTS;
    float l[NC];
    float mx = -1e30f;
    #pragma unroll
    for (int c = 0; c < NC; ++c) { l[c] = lb[c * NPTS + n]; mx = fmaxf(mx, l[c]); }
    float sum = 0.f;
    #pragma unroll
    for (int c = 0; c < NC; ++c) { l[c] = __expf(l[c] - mx); sum += l[c]; }
    float inv = 1.0f / sum;
    #pragma unroll
    for (int c = 0; c < NC; ++c) l[c] *= inv;

    float4* dst = probst + (size_t)gid * 4;
    dst[0] = make_float4(l[0], l[1], l[2], l[3]);
    dst[1] = make_float4(l[4], l[5], l[6], l[7]);
    dst[2] = make_float4(l[8], l[9], l[10], l[11]);
    dst[3] = make_float4(l[12], 0.f, 0.f, 0.f);   // pads contribute |0-0| = 0
}

// ---------------- prep 2: exclusive prefix per batch (512 cells) ----------------
__global__ __launch_bounds__(512) void prefix_kernel(const unsigned* __restrict__ hist,
                                                     unsigned* __restrict__ ofs) {
    __shared__ unsigned s[512];
    int b = blockIdx.x, t = threadIdx.x;
    unsigned v = hist[b * 512 + t];
    s[t] = v; __syncthreads();
    for (int d = 1; d < 512; d <<= 1) {
        unsigned u = (t >= d) ? s[t - d] : 0u;
        __syncthreads();
        s[t] += u;
        __syncthreads();
    }
    ofs[b * 512 + t] = s[t] - v;                  // exclusive
}

// ---------------- prep 3: scatter into sorted order ----------------
__global__ __launch_bounds__(256) void scatter_kernel(
    const float* __restrict__ xyz, unsigned* __restrict__ ofs,
    float4* __restrict__ spts, unsigned short* __restrict__ sid)
{
    int gid = blockIdx.x * 256 + threadIdx.x;
    int b = gid >> 13, n = gid & (NPTS - 1);
    const float* xb = xyz + b * 3 * NPTS;
    float x = xb[n], y = xb[NPTS + n], z = xb[2 * NPTS + n];
    float w = -0.5f * (x * x + y * y + z * z);
    unsigned pos = atomicAdd(&ofs[b * 512 + cellcode(x, y, z)], 1u);
    spts[b * NPTS + pos] = make_float4(x, y, z, w);
    sid[b * NPTS + pos] = (unsigned short)n;
}

// ---------------- prep 4: per-tile AABBs (wave per 64-pt tile) ----------------
__global__ __launch_bounds__(256) void bbox_kernel(
    const float4* __restrict__ spts, float4* __restrict__ bbmin, float4* __restrict__ bbmax)
{
    int gw = blockIdx.x * 4 + (threadIdx.x >> 6);   // global tile id (512 total)
    int lane = threadIdx.x & 63;
    float4 p = spts[gw * 64 + lane];
    float ax = p.x, ay = p.y, az = p.z, bx = p.x, by = p.y, bz = p.z;
    #pragma unroll
    for (int mk = 1; mk < 64; mk <<= 1) {
        ax = fminf(ax, __shfl_xor(ax, mk)); bx = fmaxf(bx, __shfl_xor(bx, mk));
        ay = fminf(ay, __shfl_xor(ay, mk)); by = fmaxf(by, __shfl_xor(by, mk));
        az = fminf(az, __shfl_xor(az, mk)); bz = fmaxf(bz, __shfl_xor(bz, mk));
    }
    if (lane == 0) {
        bbmin[gw] = make_float4(ax, ay, az, 0.f);
        bbmax[gw] = make_float4(bx, by, bz, 0.f);
    }
}

// ---------------- kernel B: culled exact top-16 + loss ----------------
// 256 threads = 4 waves; wave owns 4 sorted queries; lanes point-parallel.
// grid = NB * NPTS / RPB = 2048 blocks -> 8 blocks/CU.
__global__ __launch_bounds__(256, 8) void topk_loss_kernel(
    const float4* __restrict__ spts, const unsigned short* __restrict__ sid,
    const float4* __restrict__ bbmin, const float4* __restrict__ bbmax,
    const float* __restrict__ rgb, const float4* __restrict__ probst,
    float* __restrict__ partials)
{
    __shared__ unsigned s_cnt[RPB];
    __shared__ ull s_list[RPB][CAPP];    // 19.3 KB padded
    __shared__ float s_wred[4];

    const int tid = threadIdx.x;
    const int w = tid >> 6, lane = tid & 63;
    const int b = blockIdx.x >> 9;                // 512 blocks per batch
    const int nbase = (blockIdx.x & 511) * RPB;   // first sorted query position
    const int rw = w * 4;
    const int sb = b * NPTS;
    const float4* sp = spts + sb;

    if (tid < RPB) s_cnt[tid] = 0;
    __syncthreads();

    // wave-uniform queries -> SGPRs
    float qx[4], qy[4], qz[4], qn2[4];
    #pragma unroll
    for (int r = 0; r < 4; ++r) {
        float4 Q = sp[nbase + rw + r];
        qx[r] = rfl(Q.x); qy[r] = rfl(Q.y); qz[r] = rfl(Q.z);
        qn2[r] = rfl(-2.0f * Q.w);                // ||q||^2
    }

    // ---- init scan: WIN adjacent sorted tiles (spatially near) ----
    int twlo = (nbase >> 6) - (WIN / 2);
    twlo = max(0, min(twlo, NTILES - WIN));

    float bk[4];
    #pragma unroll
    for (int r = 0; r < 4; ++r) bk[r] = -3.0e38f;
    #pragma unroll
    for (int it = 0; it < WIN; ++it) {
        float4 P = sp[(twlo + it) * 64 + lane];
        #pragma unroll
        for (int r = 0; r < 4; ++r) {
            float s = fmaf(qx[r], P.x, fmaf(qy[r], P.y, fmaf(qz[r], P.z, P.w)));
            bk[r] = fmaxf(bk[r], s);
        }
    }

    // ---- threshold: min over 8 buckets of bucket top-2 => thr <= s_(16) ----
    float thr[4], Dcull[4];
    #pragma unroll
    for (int r = 0; r < 4; ++r) {
        float m1 = bk[r], m2 = -3.0e38f;
        #pragma unroll
        for (int mk = 1; mk < 8; mk <<= 1) {
            float p1 = __shfl_xor(m1, mk), p2 = __shfl_xor(m2, mk);
            float lo = fminf(m1, p1);
            m1 = fmaxf(m1, p1);
            m2 = fmaxf(lo, fmaxf(m2, p2));
        }
        #pragma unroll
        for (int mk = 8; mk < 64; mk <<= 1)
            m2 = fminf(m2, __shfl_xor(m2, mk));
        thr[r] = rfl(m2);
        Dcull[r] = (qn2[r] - 2.0f * thr[r]) * 1.0001f + 1e-6f;   // >= d16^2, fp-safe
    }

    // ---- tile cull: lane tests tiles (lane) and (64+lane) ----
    ull m0 = 0, m1m = 0;
    #pragma unroll
    for (int half = 0; half < 2; ++half) {
        int t = half * 64 + lane;
        bool pass = false;
        if (t < twlo || t >= twlo + WIN) {        // init window already scanned
            float4 bmn = bbmin[b * NTILES + t];
            float4 bmx = bbmax[b * NTILES + t];
            #pragma unroll
            for (int r = 0; r < 4; ++r) {
                float dx = fmaxf(0.f, fmaxf(bmn.x - qx[r], qx[r] - bmx.x));
                float dy = fmaxf(0.f, fmaxf(bmn.y - qy[r], qy[r] - bmx.y));
                float dz = fmaxf(0.f, fmaxf(bmn.z - qz[r], qz[r] - bmx.z));
                float md = fmaf(dx, dx, fmaf(dy, dy, dz * dz));
                pass |= (md <= Dcull[r]);
            }
        }
        ull mk = __ballot(pass);
        if (half) m1m = mk; else m0 = mk;
    }

    // ---- append candidates (s >= thr) from init window + passing tiles ----
    auto append_tile = [&](int T) {
        float4 P = sp[T * 64 + lane];
        int m = sid[sb + T * 64 + lane];
        #pragma unroll
        for (int r = 0; r < 4; ++r) {
            float s = fmaf(qx[r], P.x, fmaf(qy[r], P.y, fmaf(qz[r], P.z, P.w)));
            if (s >= thr[r]) {
                int row = rw + r;
                unsigned slot = atomicAdd(&s_cnt[row], 1u);
                if (slot < CAP)
                    s_list[row][slot] = ((ull)sortable(s) << 13) | (ull)(8191 - m);
            }
        }
    };
    #pragma unroll
    for (int it = 0; it < WIN; ++it) append_tile(twlo + it);
    while (m0)  { int t = __ffsll(m0) - 1;  m0  &= m0 - 1;  append_tile(t); }
    while (m1m) { int t = __ffsll(m1m) - 1; m1m &= m1m - 1; append_tile(64 + t); }
    __syncthreads();

    // ---- phase 3: rank-count selection + loss terms (16 lanes per row) ----
    const int row = tid >> 4;            // 0..15
    const int i0 = tid & 15;
    const int cnt = min((int)s_cnt[row], CAP);    // >= 16 guaranteed
    const int cid = sid[sb + nbase + row];        // original center id

    const float* rb = rgb + b * 3 * NPTS;
    float crx = rb[cid], cry = rb[NPTS + cid], crz = rb[2 * NPTS + cid];
    const float4* cp = probst + (size_t)(sb + cid) * 4;
    float4 cp0 = cp[0], cp1 = cp[1], cp2 = cp[2], cp3 = cp[3];

    float acc = 0.f;
    for (int j = i0; j < cnt; j += 16) {
        ull kj = s_list[row][j];
        int rank = 0;
        for (int j2 = 0; j2 < cnt; ++j2) rank += (s_list[row][j2] > kj);
        if (rank < KTOP) {                        // exact top-16 member
            int m = 8191 - (int)(kj & 0x1FFFull);
            float nrx = rb[m], nry = rb[NPTS + m], nrz = rb[2 * NPTS + m];
            const float4* np4 = probst + (size_t)(sb + m) * 4;
            float4 q0 = np4[0], q1 = np4[1], q2 = np4[2], q3 = np4[3];
            float dx = crx - nrx, dy = cry - nry, dz = crz - nrz;
            float rd = sqrtf(fmaf(dx, dx, fmaf(dy, dy, dz * dz)));
            float pd = fabsf(cp0.x-q0.x)+fabsf(cp0.y-q0.y)+fabsf(cp0.z-q0.z)+fabsf(cp0.w-q0.w)
                     + fabsf(cp1.x-q1.x)+fabsf(cp1.y-q1.y)+fabsf(cp1.z-q1.z)+fabsf(cp1.w-q1.w)
                     + fabsf(cp2.x-q2.x)+fabsf(cp2.y-q2.y)+fabsf(cp2.z-q2.z)+fabsf(cp2.w-q2.w)
                     + fabsf(cp3.x-q3.x)+fabsf(cp3.y-q3.y)+fabsf(cp3.z-q3.z)+fabsf(cp3.w-q3.w);
            acc = fmaf(__expf(-10.0f * rd), pd, acc);
        }
    }

    // fixed-tree deterministic reduce: wave -> block -> partials
    #pragma unroll
    for (int off = 32; off > 0; off >>= 1) acc += __shfl_down(acc, off);
    if (lane == 0) s_wred[w] = acc;
    __syncthreads();
    if (tid == 0) partials[blockIdx.x] = s_wred[0] + s_wred[1] + s_wred[2] + s_wred[3];
}

// ---------------- kernel C: final reduce (2048 partials) ----------------
__global__ __launch_bounds__(256) void reduce_kernel(const float* __restrict__ partials,
                                                     float* __restrict__ out) {
    __shared__ float s[256];
    int tid = threadIdx.x;
    float v = 0.f;
    #pragma unroll
    for (int i = 0; i < 8; ++i) v += partials[tid + 256 * i];
    s[tid] = v;
    __syncthreads();
    if (tid < 128) s[tid] += s[tid + 128];
    __syncthreads();
    if (tid < 64) {
        float x = s[tid] + s[tid + 64];
        for (int off = 32; off > 0; off >>= 1) x += __shfl_down(x, off);
        if (tid == 0) out[0] = x * (1.0f / (float)(NB * NPTS * KTOP));
    }
}

extern "C" void kernel_launch(void* const* d_in, const int* in_sizes, int n_in,
                              void* d_out, int out_size, void* d_ws, size_t ws_size,
                              hipStream_t stream) {
    (void)in_sizes; (void)n_in; (void)out_size; (void)ws_size;
    const float* logits = (const float*)d_in[0];
    const float* xyz    = (const float*)d_in[1];
    const float* rgb    = (const float*)d_in[2];

    // workspace layout (floats): total ~2.73 MB
    float4* spts   = (float4*)d_ws;                         // 32768 f4 (512 KB)
    float4* probst = spts + NB * NPTS;                      // 131072 f4 (2 MB)
    float4* bbmin  = probst + (size_t)NB * NPTS * 4;        // 512 f4
    float4* bbmax  = bbmin + NB * NTILES;                   // 512 f4
    unsigned* hist = (unsigned*)(bbmax + NB * NTILES);      // 2048 u32
    unsigned* ofs  = hist + NB * 512;                       // 2048 u32
    unsigned short* sid = (unsigned short*)(ofs + NB * 512);// 32768 u16
    float* partials = (float*)(sid + NB * NPTS);            // 2048 f

    zero_kernel<<<8, 256, 0, stream>>>(hist);
    hist_kernel<<<NB * NPTS / 256, 256, 0, stream>>>(logits, xyz, hist, probst);
    prefix_kernel<<<NB, 512, 0, stream>>>(hist, ofs);
    scatter_kernel<<<NB * NPTS / 256, 256, 0, stream>>>(xyz, ofs, spts, sid);
    bbox_kernel<<<NB * NTILES / 4, 256, 0, stream>>>(spts, bbmin, bbmax);
    topk_loss_kernel<<<NB * NPTS / RPB, 256, 0, stream>>>(spts, sid, bbmin, bbmax,
                                                          rgb, probst, partials);
    reduce_kernel<<<1, 256, 0, stream>>>(partials, (float*)d_out);
}